// Round 3
// baseline (226.583 us; speedup 1.0000x reference)
//
#include <hip/hip_runtime.h>
#include <cmath>

#define HW 256
#define NIMG 48
#define NCH 3
#define NPLANE (NIMG * NCH)
#define STRIP 16
#define NSTRIP 16
#define NBLOCKS (NPLANE * NSTRIP)

// ws doubles: ws[0]=sum dssim, ws[1]=sum |diff|, ws[2]=sum w*|diff|, ws[3]=done counter
__global__ void zero_ws_kernel(double* ws) {
    if (threadIdx.x < 4) ws[threadIdx.x] = 0.0;
}

// ---------------------------------------------------------------------------
// Fused SSIM + L1 + weighted-L1, latency-hiding structure:
//  - one block = 16-row output strip of one (n,c) plane (26 input rows)
//  - 11-slot rotating LDS row buffer, slot = input_iter % 11 (compile-time):
//    slot's previous reader was 11 barriers ago -> ONE barrier per row
//  - next row prefetched into registers BEFORE the barrier -> global-load
//    latency hidden behind a full row of h-conv/v-pass compute
//  - v-pass via 11-slot register ring, compile-time cyclic indexing
//  - last finishing block computes the final scalar (no 3rd dispatch)
// ---------------------------------------------------------------------------
__launch_bounds__(256)
__global__ void fused_kernel(const float* __restrict__ pred,
                             const float* __restrict__ target,
                             const float* __restrict__ lmk,
                             double* __restrict__ ws,
                             float* __restrict__ out)
{
    const int plane = blockIdx.x;          // n*3 + c
    const int n     = plane / 3;
    const int r0    = blockIdx.y * STRIP;
    const int x     = threadIdx.x;

    __shared__ float2 spt[11][HW + 10];    // rotating (p,t) rows, 5-wide pads
    __shared__ float  sxc[STRIP][24];      // crossing x per (row, edge)
    __shared__ float  slm[48];
    __shared__ float  sbbs[12];
    __shared__ float  svalids[3];
    __shared__ float  red[12];

    // Gaussian weights (same fp32 math as reference; constant-foldable)
    float g[11];
    {
        float gs = 0.f;
#pragma unroll
        for (int i = 0; i < 11; ++i) {
            float c = (float)i - 5.0f;
            g[i] = expf(-c * c / 4.5f);
            gs += g[i];
        }
#pragma unroll
        for (int i = 0; i < 11; ++i) g[i] /= gs;
    }

    // ---- prologue: landmarks, bboxes, crossing table, pad init -------------
    if (x < 48) slm[x] = lmk[n * 136 + 72 + x];
    // zero the column pads once (never overwritten afterwards)
    if (x < 55) {
        int t = x / 5, q = x % 5;
        spt[t][q] = make_float2(0.f, 0.f);
        spt[t][261 + q] = make_float2(0.f, 0.f);
    } else if (x >= 200 && x < 255) {
        int idx = x - 200;
        int t = idx / 5, q = idx % 5;
        (void)t; (void)q;   // second half of pads handled below for t>=? (t<11 covered above? 55 covers t=0..10 ✓)
    }
    __syncthreads();

    if (x < 3) {
        const int s0 = (x == 0) ? 0 : (x == 1) ? 6 : 12;
        const int L  = (x == 2) ? 12 : 6;
        float xmn = 3e38f, xmx = -3e38f, ymn = 3e38f, ymx = -3e38f;
        for (int i = 0; i < L; ++i) {
            float px = slm[2 * (s0 + i)], py = slm[2 * (s0 + i) + 1];
            xmn = fminf(xmn, px); xmx = fmaxf(xmx, px);
            ymn = fminf(ymn, py); ymx = fmaxf(ymx, py);
        }
        xmn = floorf(xmn); xmx = floorf(xmx); ymn = floorf(ymn); ymx = floorf(ymx);
        sbbs[4 * x + 0] = xmn; sbbs[4 * x + 1] = xmx;
        sbbs[4 * x + 2] = ymn; sbbs[4 * x + 3] = ymx;
        svalids[x] = (xmn >= 0.f && ymn >= 0.f && xmx < 256.f && ymx < 256.f) ? 1.f : 0.f;
    }

#pragma unroll
    for (int u = 0; u < 2; ++u) {
        int idx = x + 256 * u;
        if (idx < STRIP * 24) {
            int r = idx / 24, e = idx - r * 24;
            float Y = (float)(r0 + r);
            const int s0 = (e < 6) ? 0 : (e < 12) ? 6 : 12;
            const int L  = (e < 12) ? 6 : 12;
            int il = e - s0;
            int i2 = (il + 1 == L) ? 0 : il + 1;
            float x1 = slm[2 * (s0 + il)], y1 = slm[2 * (s0 + il) + 1];
            float x2 = slm[2 * (s0 + i2)], y2 = slm[2 * (s0 + i2) + 1];
            bool crossing = (y1 > Y) != (y2 > Y);
            float xc = (x2 - x1) * (Y - y1) / (y2 - y1 + 1e-6f) + x1;
            sxc[r][e] = crossing ? xc : -3e38f;
        }
    }
    // (visibility of sxc/sbbs covered by the barrier inside iteration 0)

    const float* __restrict__ pp = pred   + (size_t)plane * (HW * HW);
    const float* __restrict__ tp = target + (size_t)plane * (HW * HW);

    float ring[11][5];
#pragma unroll
    for (int s = 0; s < 11; ++s)
#pragma unroll
        for (int q = 0; q < 5; ++q) ring[s][q] = 0.f;

    float acc = 0.f, accl1 = 0.f, acclw = 0.f;
    const float X = (float)x;

    // prefetch input row for i=0 (row r0-5)
    float pv = 0.f, tv = 0.f;
    {
        int r = r0 - 5;
        if (r >= 0) { pv = pp[r * HW + x]; tv = tp[r * HW + x]; }
    }

    // ---- main loop: 26 input rows = 2 chunks of 11 + tail of 4 -------------
#define ROW_BODY(T_SLOT, I_EXPR, DO_PREFETCH)                                   \
    {                                                                           \
        const int i = (I_EXPR);                                                 \
        spt[T_SLOT][x + 5] = make_float2(pv, tv);                               \
        if (DO_PREFETCH) {                                                      \
            int r = r0 - 4 + i;                                                 \
            float npv = 0.f, ntv = 0.f;                                         \
            if (r >= 0 && r < HW) { npv = pp[r * HW + x]; ntv = tp[r * HW + x]; } \
            pv = npv; tv = ntv;                                                 \
        }                                                                       \
        __syncthreads();                                                        \
        float h0 = 0.f, h1 = 0.f, h2 = 0.f, h3 = 0.f, h4 = 0.f;                 \
        float2 center = make_float2(0.f, 0.f);                                  \
        _Pragma("unroll")                                                       \
        for (int k = 0; k < 11; ++k) {                                          \
            float2 v = spt[T_SLOT][x + k];                                      \
            if (k == 5) center = v;                                             \
            float w = g[k];                                                     \
            float wp = w * v.x, wt = w * v.y;                                   \
            h0 += wp;                                                           \
            h1 += wt;                                                           \
            h2 = fmaf(wp, v.x, h2);                                             \
            h3 = fmaf(wt, v.y, h3);                                             \
            h4 = fmaf(wp, v.y, h4);                                             \
        }                                                                       \
        ring[T_SLOT][0] = h0; ring[T_SLOT][1] = h1; ring[T_SLOT][2] = h2;       \
        ring[T_SLOT][3] = h3; ring[T_SLOT][4] = h4;                             \
        if (i >= 5 && i < 5 + STRIP) {                                          \
            float ad = fabsf(center.x - center.y);                              \
            accl1 += ad;                                                        \
            float Y = (float)(r0 + i - 5);                                      \
            float wgt = 1.f;                                                    \
            bool any0 = (svalids[0] != 0.f) && (Y >= sbbs[2])  && (Y < sbbs[3]);   \
            bool any1 = (svalids[1] != 0.f) && (Y >= sbbs[6])  && (Y < sbbs[7]);   \
            bool any2 = (svalids[2] != 0.f) && (Y >= sbbs[10]) && (Y < sbbs[11]);  \
            if (any0 || any1 || any2) {                                         \
                const float* xc = sxc[i - 5];                                   \
                int c0 = 0, c1 = 0, c2 = 0;                                     \
                _Pragma("unroll")                                               \
                for (int e = 0; e < 6; ++e)   c0 += (X < xc[e]) ? 1 : 0;        \
                _Pragma("unroll")                                               \
                for (int e = 6; e < 12; ++e)  c1 += (X < xc[e]) ? 1 : 0;        \
                _Pragma("unroll")                                               \
                for (int e = 12; e < 24; ++e) c2 += (X < xc[e]) ? 1 : 0;        \
                if (any0 && (c0 & 1) && X >= sbbs[0] && X < sbbs[1]) wgt += 3.f; \
                if (any1 && (c1 & 1) && X >= sbbs[4] && X < sbbs[5]) wgt += 3.f; \
                if (any2 && (c2 & 1) && X >= sbbs[8] && X < sbbs[9]) wgt += 2.f; \
            }                                                                   \
            acclw += wgt * ad;                                                  \
        }                                                                       \
        if (i >= 10) {                                                          \
            float mux = 0.f, muy = 0.f, exx = 0.f, eyy = 0.f, exy = 0.f;        \
            _Pragma("unroll")                                                   \
            for (int j = 0; j < 11; ++j) {                                      \
                const int s = (T_SLOT + 1 + j) % 11;                            \
                float w = g[j];                                                 \
                mux = fmaf(w, ring[s][0], mux);                                 \
                muy = fmaf(w, ring[s][1], muy);                                 \
                exx = fmaf(w, ring[s][2], exx);                                 \
                eyy = fmaf(w, ring[s][3], eyy);                                 \
                exy = fmaf(w, ring[s][4], exy);                                 \
            }                                                                   \
            float sx  = exx - mux * mux;                                        \
            float sy  = eyy - muy * muy;                                        \
            float sxy = exy - mux * muy;                                        \
            const float C1 = 1e-4f, C2 = 9e-4f;                                 \
            float num = (2.f * mux * muy + C1) * (2.f * sxy + C2);              \
            float den = (mux * mux + muy * muy + C1) * (sx + sy + C2);          \
            acc += 0.5f * (1.f - num / (den + 1e-8f));                          \
        }                                                                       \
    }

    for (int c = 0; c < 2; ++c) {
#pragma unroll
        for (int t = 0; t < 11; ++t) {
            ROW_BODY(t, 11 * c + t, true)
        }
    }
#pragma unroll
    for (int t = 0; t < 4; ++t) {
        ROW_BODY(t, 22 + t, (t < 3))
    }
#undef ROW_BODY

    // ---- block reduction + global accumulate + last-block finalize ---------
#pragma unroll
    for (int off = 32; off > 0; off >>= 1) {
        acc   += __shfl_down(acc, off, 64);
        accl1 += __shfl_down(accl1, off, 64);
        acclw += __shfl_down(acclw, off, 64);
    }
    if ((x & 63) == 0) {
        int w = x >> 6;
        red[w] = acc; red[4 + w] = accl1; red[8 + w] = acclw;
    }
    __syncthreads();
    if (x == 0) {
        atomicAdd(&ws[0], (double)red[0] + red[1] + red[2] + red[3]);
        atomicAdd(&ws[1], (double)red[4] + red[5] + red[6] + red[7]);
        atomicAdd(&ws[2], (double)red[8] + red[9] + red[10] + red[11]);
        __threadfence();
        unsigned prev = atomicAdd((unsigned*)&ws[3], 1u);
        if (prev == NBLOCKS - 1) {
            // atomic reads guarantee coherent view of all blocks' sums
            double s0 = atomicAdd(&ws[0], 0.0);
            double s1 = atomicAdd(&ws[1], 0.0);
            double s2 = atomicAdd(&ws[2], 0.0);
            const double denom = (double)NIMG * NCH * HW * HW;
            out[0] = (float)((10.0 * s0 + 10.0 * s1 + 5.0 * s2) / denom);
        }
    }
}

// ---------------------------------------------------------------------------
extern "C" void kernel_launch(void* const* d_in, const int* in_sizes, int n_in,
                              void* d_out, int out_size, void* d_ws, size_t ws_size,
                              hipStream_t stream)
{
    const float* pred   = (const float*)d_in[0];
    const float* target = (const float*)d_in[1];
    const float* lmk    = (const float*)d_in[2];
    float* out  = (float*)d_out;
    double* ws  = (double*)d_ws;

    hipLaunchKernelGGL(zero_ws_kernel, dim3(1), dim3(64), 0, stream, ws);
    hipLaunchKernelGGL(fused_kernel, dim3(NPLANE, NSTRIP), dim3(256), 0, stream,
                       pred, target, lmk, ws, out);
}